// Round 8
// baseline (2288.124 us; speedup 1.0000x reference)
//
#include <hip/hip_runtime.h>

#define N_NODES 100000
#define N_EDGES 3200000
#define IN_CH 128
#define HID_CH 64
#define OUT_CH 32

#define BSHIFT 7
#define BNODES 128                                   // nodes per bucket
#define NBUCK ((N_NODES + BNODES - 1) / BNODES)      // 782
#define PCHUNK 6144                                  // edges per partition WG
#define NPCHK ((N_EDGES + PCHUNK - 1) / PCHUNK)      // 521

typedef unsigned long long ull;
typedef unsigned int u32;
typedef _Float16 h2v __attribute__((ext_vector_type(2)));   // half2

// ---------------- partition pass 1: global bucket counts ----------------
__global__ __launch_bounds__(256) void pcount_kernel(const int* __restrict__ dst,
                                                     u32* __restrict__ gcnt, int nE) {
    __shared__ u32 cntL[NBUCK];
    int tid = threadIdx.x;
    for (int i = tid; i < NBUCK; i += 256) cntL[i] = 0;
    __syncthreads();
    int e0 = blockIdx.x * PCHUNK;
    for (int i = tid; i < PCHUNK; i += 256) {
        int e = e0 + i;
        if (e < nE) atomicAdd(&cntL[dst[e] >> BSHIFT], 1u);
    }
    __syncthreads();
    for (int i = tid; i < NBUCK; i += 256)
        if (cntL[i]) atomicAdd(&gcnt[i], cntL[i]);
}

// ---------------- partition pass 2: scan bucket counts -> base, cursor ----------------
__global__ __launch_bounds__(256) void scanb_kernel(const u32* __restrict__ gcnt,
                                                    int* __restrict__ base,
                                                    int* __restrict__ gcur) {
    __shared__ int temp[256];
    int tid = threadIdx.x;
    int c[4]; int s = 0;
#pragma unroll
    for (int k = 0; k < 4; ++k) {
        int j = tid * 4 + k;
        c[k] = (j < NBUCK) ? (int)gcnt[j] : 0;
        s += c[k];
    }
    temp[tid] = s; __syncthreads();
    for (int d = 1; d < 256; d <<= 1) {
        int v = (tid >= d) ? temp[tid - d] : 0; __syncthreads();
        temp[tid] += v; __syncthreads();
    }
    int run = temp[tid] - s;   // exclusive
#pragma unroll
    for (int k = 0; k < 4; ++k) {
        int j = tid * 4 + k;
        if (j < NBUCK) { base[j] = run; gcur[j] = run; }
        run += c[k];
    }
    if (tid == 255) base[NBUCK] = run;   // == nE
}

// ---------------- partition pass 3: LDS-staged scatter into bucket-major COO ----------------
// record: .x = src(17b) | dstLocal(7b)<<17 ; .y = w as float (16-bit quantized)
__global__ __launch_bounds__(256) void pscatter_kernel(const int* __restrict__ src,
                                                       const int* __restrict__ dst,
                                                       const float* __restrict__ w,
                                                       int* __restrict__ gcur,
                                                       int2* __restrict__ eout, int nE) {
    __shared__ ull staging[PCHUNK];   // src17 | dst17<<17 | w16<<34
    __shared__ u32 cntL[NBUCK];       // counts, later per-chunk global segment base
    __shared__ u32 ofsL[NBUCK];
    __shared__ u32 curL[NBUCK];
    __shared__ int temp[256];
    int tid = threadIdx.x;
    int e0 = blockIdx.x * PCHUNK;
    int nb = nE - e0; if (nb > PCHUNK) nb = PCHUNK;

    for (int i = tid; i < NBUCK; i += 256) cntL[i] = 0;
    __syncthreads();
    // local histogram
    for (int i = tid; i < PCHUNK; i += 256) {
        int e = e0 + i;
        if (e < nE) atomicAdd(&cntL[dst[e] >> BSHIFT], 1u);
    }
    __syncthreads();
    // local exclusive scan -> ofsL (frozen) + curL (mutable)
    int c[4]; int s = 0;
#pragma unroll
    for (int k = 0; k < 4; ++k) {
        int j = tid * 4 + k;
        c[k] = (j < NBUCK) ? (int)cntL[j] : 0;
        s += c[k];
    }
    temp[tid] = s; __syncthreads();
    for (int d = 1; d < 256; d <<= 1) {
        int v = (tid >= d) ? temp[tid - d] : 0; __syncthreads();
        temp[tid] += v; __syncthreads();
    }
    int run = temp[tid] - s;
#pragma unroll
    for (int k = 0; k < 4; ++k) {
        int j = tid * 4 + k;
        if (j < NBUCK) { ofsL[j] = (u32)run; curL[j] = (u32)run; }
        run += c[k];
    }
    __syncthreads();
    // stage records grouped by bucket
    for (int i = tid; i < PCHUNK; i += 256) {
        int e = e0 + i;
        if (e < nE) {
            int d = dst[e];
            u32 w16 = (u32)(w[e] * 65535.f + 0.5f); if (w16 > 65535u) w16 = 65535u;
            u32 slot = atomicAdd(&curL[d >> BSHIFT], 1u);
            staging[slot] = (ull)(u32)src[e] | ((ull)(u32)d << 17) | ((ull)w16 << 34);
        }
    }
    __syncthreads();
    // reserve global ranges per bucket (cntL := this chunk's global segment base)
    for (int b = tid; b < NBUCK; b += 256) {
        u32 cc = curL[b] - ofsL[b];
        if (cc) cntL[b] = (u32)atomicAdd(&gcur[b], (int)cc);
    }
    __syncthreads();
    // coalesced flush (bucket-grouped staging -> contiguous global segments)
    for (int sI = tid; sI < nb; sI += 256) {
        ull r = staging[sI];
        int srcn = (int)(r & 0x1FFFF);
        int d    = (int)((r >> 17) & 0x1FFFF);
        u32 w16  = (u32)((r >> 34) & 0xFFFF);
        int b = d >> BSHIFT;
        int dest = (int)cntL[b] + (sI - (int)ofsL[b]);
        float wf = (float)w16 * (1.f / 65535.f);
        eout[dest] = make_int2(srcn | ((d & (BNODES - 1)) << 17), __float_as_int(wf));
    }
}

// ---------------- weighted degree per bucket -> dinv (no global atomics) ----------------
__global__ __launch_bounds__(256) void dega_kernel(const int* __restrict__ base,
                                                   const int2* __restrict__ eout,
                                                   float* __restrict__ dinv, int n) {
    __shared__ float degL[BNODES];
    int tid = threadIdx.x, b = blockIdx.x;
    if (tid < BNODES) degL[tid] = 0.f;
    __syncthreads();
    int beg = base[b], end = base[b + 1];
    for (int i = beg + tid; i < end; i += 256) {
        int2 rec = eout[i];
        atomicAdd(&degL[(rec.x >> 17) & (BNODES - 1)], __int_as_float(rec.y));
    }
    __syncthreads();
    int node = b * BNODES + tid;
    if (tid < BNODES && node < n) dinv[node] = rsqrtf(degL[tid] + 1.f);
}

// ---------------- gemm1: g1[n] = dinv[n] * (x[n] @ W1), fp16 ----------------
__global__ __launch_bounds__(256) void gemm1_kernel(const float* __restrict__ X,
                                                    const float* __restrict__ Wm,
                                                    const float* __restrict__ dinv,
                                                    _Float16* __restrict__ G, int n) {
    constexpr int INC = IN_CH, OUTC = HID_CH, TN = OUTC / 16;
    __shared__ float Ws[INC][OUTC];
    __shared__ float Xs[64][INC + 4];

    const int tid = threadIdx.x;
    const int row0 = blockIdx.x * 64;

    for (int i = tid; i < INC * OUTC / 4; i += 256)
        reinterpret_cast<float4*>(&Ws[0][0])[i] = reinterpret_cast<const float4*>(Wm)[i];
    for (int i = tid; i < 64 * INC / 4; i += 256) {
        int r = i / (INC / 4);
        int c = (i % (INC / 4)) * 4;
        float4 v = make_float4(0.f, 0.f, 0.f, 0.f);
        if (row0 + r < n)
            v = *reinterpret_cast<const float4*>(X + (size_t)(row0 + r) * INC + c);
        *reinterpret_cast<float4*>(&Xs[r][c]) = v;
    }
    __syncthreads();

    const int cg = tid & 15;
    const int rg = tid >> 4;

    float acc[4][TN];
#pragma unroll
    for (int i = 0; i < 4; ++i)
#pragma unroll
        for (int j = 0; j < TN; ++j) acc[i][j] = 0.f;

    for (int k = 0; k < INC; ++k) {
        float wv[TN];
#pragma unroll
        for (int j = 0; j < TN; ++j) wv[j] = Ws[k][cg * TN + j];
#pragma unroll
        for (int i = 0; i < 4; ++i) {
            float xv = Xs[rg * 4 + i][k];
#pragma unroll
            for (int j = 0; j < TN; ++j) acc[i][j] = fmaf(xv, wv[j], acc[i][j]);
        }
    }

#pragma unroll
    for (int i = 0; i < 4; ++i) {
        int row = row0 + rg * 4 + i;
        if (row < n) {
            float di = dinv[row];
#pragma unroll
            for (int j = 0; j < TN; ++j)
                G[(size_t)row * OUTC + cg * TN + j] = (_Float16)(di * acc[i][j]);
        }
    }
}

// ---------------- layer1 aggregate: LDS acc, hidden+ReLU, fused GEMM2 -> g2h ----------------
// acc = sum_e w * g1[src]; hidden = relu(di*(acc + g1[node]) + b1); g2h = di * (hidden @ W2)
__global__ __launch_bounds__(256) void agg1_kernel(const int* __restrict__ base,
                                                   const int2* __restrict__ eout,
                                                   const h2v* __restrict__ g1,
                                                   const float* __restrict__ dinv,
                                                   const float* __restrict__ b1,
                                                   const float* __restrict__ W2,
                                                   _Float16* __restrict__ g2h, int n) {
    __shared__ float accL[BNODES][HID_CH];   // 32KB
    __shared__ float W2s[HID_CH * OUT_CH];   // 8KB
    int tid = threadIdx.x, b = blockIdx.x;
    int node0 = b * BNODES;

    for (int i = tid; i < BNODES * HID_CH; i += 256) (&accL[0][0])[i] = 0.f;
    for (int i = tid; i < HID_CH * OUT_CH; i += 256) W2s[i] = W2[i];
    __syncthreads();

    int beg = base[b], end = base[b + 1];
    int sub = tid >> 5;        // 8 concurrent edges
    int p = tid & 31;          // channel pair
    for (int e = beg + sub; e < end; e += 8) {
        int2 rec = eout[e];
        int srcn = rec.x & 0x1FFFF;
        int dl = (rec.x >> 17) & (BNODES - 1);
        float wgt = __int_as_float(rec.y);
        h2v hv = g1[(size_t)srcn * 32 + p];
        atomicAdd(&accL[dl][2 * p],     wgt * (float)hv.x);
        atomicAdd(&accL[dl][2 * p + 1], wgt * (float)hv.y);
    }
    __syncthreads();

    // hidden + ReLU in place
    for (int lin = tid; lin < BNODES * 32; lin += 256) {
        int nl = lin >> 5, pp = lin & 31;
        int node = node0 + nl;
        float hx = 0.f, hy = 0.f;
        if (node < n) {
            float di = dinv[node];
            h2v sv = g1[(size_t)node * 32 + pp];
            float2 bp = reinterpret_cast<const float2*>(b1)[pp];
            hx = fmaxf(di * (accL[nl][2 * pp]     + (float)sv.x) + bp.x, 0.f);
            hy = fmaxf(di * (accL[nl][2 * pp + 1] + (float)sv.y) + bp.y, 0.f);
        }
        accL[nl][2 * pp] = hx; accL[nl][2 * pp + 1] = hy;
    }
    __syncthreads();

    // fused GEMM2 from LDS: 8 nodes x 32 outputs concurrently
    int o = tid & 31;
    for (int rnd = 0; rnd < BNODES / 8; ++rnd) {
        int nl = rnd * 8 + (tid >> 5);
        int node = node0 + nl;
        float acc2 = 0.f;
#pragma unroll
        for (int cc = 0; cc < HID_CH; ++cc)
            acc2 = fmaf(accL[nl][cc], W2s[cc * OUT_CH + o], acc2);
        if (node < n) g2h[(size_t)node * OUT_CH + o] = (_Float16)(dinv[node] * acc2);
    }
}

// ---------------- layer2 aggregate: LDS acc -> out (fp32) ----------------
// out = di*(sum_e w*g2[src] + g2[node]) + b2
__global__ __launch_bounds__(256) void agg2_kernel(const int* __restrict__ base,
                                                   const int2* __restrict__ eout,
                                                   const h2v* __restrict__ g2,
                                                   const float* __restrict__ dinv,
                                                   const float* __restrict__ b2,
                                                   float* __restrict__ out, int n) {
    __shared__ float accL[BNODES][OUT_CH];   // 16KB
    int tid = threadIdx.x, b = blockIdx.x;
    int node0 = b * BNODES;

    for (int i = tid; i < BNODES * OUT_CH; i += 256) (&accL[0][0])[i] = 0.f;
    __syncthreads();

    int beg = base[b], end = base[b + 1];
    int sub = tid >> 4;        // 16 concurrent edges
    int p = tid & 15;
    for (int e = beg + sub; e < end; e += 16) {
        int2 rec = eout[e];
        int srcn = rec.x & 0x1FFFF;
        int dl = (rec.x >> 17) & (BNODES - 1);
        float wgt = __int_as_float(rec.y);
        h2v hv = g2[(size_t)srcn * 16 + p];
        atomicAdd(&accL[dl][2 * p],     wgt * (float)hv.x);
        atomicAdd(&accL[dl][2 * p + 1], wgt * (float)hv.y);
    }
    __syncthreads();

    for (int lin = tid; lin < BNODES * 16; lin += 256) {
        int nl = lin >> 4, pp = lin & 15;
        int node = node0 + nl;
        if (node < n) {
            float di = dinv[node];
            h2v sv = g2[(size_t)node * 16 + pp];
            float2 bp = reinterpret_cast<const float2*>(b2)[pp];
            float2 r;
            r.x = di * (accL[nl][2 * pp]     + (float)sv.x) + bp.x;
            r.y = di * (accL[nl][2 * pp + 1] + (float)sv.y) + bp.y;
            reinterpret_cast<float2*>(out)[(size_t)node * 16 + pp] = r;
        }
    }
}

extern "C" void kernel_launch(void* const* d_in, const int* in_sizes, int n_in,
                              void* d_out, int out_size, void* d_ws, size_t ws_size,
                              hipStream_t stream) {
    const float* x   = (const float*)d_in[0];
    const int*   ei  = (const int*)d_in[1];
    const float* w   = (const float*)d_in[2];
    const float* W1  = (const float*)d_in[3];
    const float* b1  = (const float*)d_in[4];
    const float* W2  = (const float*)d_in[5];
    const float* b2  = (const float*)d_in[6];
    float* out = (float*)d_out;

    const int* src = ei;
    const int* dst = ei + N_EDGES;

    // workspace (~45.3 MB, well under the >=67MB proven in earlier rounds)
    char* ws = (char*)d_ws;
    size_t off = 0;
    auto alloc = [&](size_t b) { size_t p = off; off += (b + 255) & ~(size_t)255; return p; };
    u32*      gcnt  = (u32*)(ws + alloc((size_t)NBUCK * 4));
    int*      base  = (int*)(ws + alloc((size_t)(NBUCK + 1) * 4));
    int*      gcur  = (int*)(ws + alloc((size_t)NBUCK * 4));
    float*    dinv  = (float*)(ws + alloc((size_t)N_NODES * 4));
    int2*     eout  = (int2*)(ws + alloc((size_t)N_EDGES * 8));
    _Float16* g1    = (_Float16*)(ws + alloc((size_t)N_NODES * HID_CH * 2));
    _Float16* g2h   = (_Float16*)(ws + alloc((size_t)N_NODES * OUT_CH * 2));

    hipMemsetAsync(gcnt, 0, (size_t)NBUCK * 4, stream);

    // partition edges into 782 dst-buckets (bucket-major COO)
    pcount_kernel<<<NPCHK, 256, 0, stream>>>(dst, gcnt, N_EDGES);
    scanb_kernel<<<1, 256, 0, stream>>>(gcnt, base, gcur);
    pscatter_kernel<<<NPCHK, 256, 0, stream>>>(src, dst, w, gcur, eout, N_EDGES);

    // weighted degree -> dinv (streaming, LDS only)
    dega_kernel<<<NBUCK, 256, 0, stream>>>(base, eout, dinv, N_NODES);

    // g1 = dinv * (x @ W1)
    gemm1_kernel<<<(N_NODES + 63) / 64, 256, 0, stream>>>(x, W1, dinv, g1, N_NODES);

    // layer1 aggregate + ReLU + fused GEMM2 -> g2h = dinv * h2
    agg1_kernel<<<NBUCK, 256, 0, stream>>>(base, eout, (const h2v*)g1, dinv, b1, W2, g2h, N_NODES);

    // layer2 aggregate -> out
    agg2_kernel<<<NBUCK, 256, 0, stream>>>(base, eout, (const h2v*)g2h, dinv, b2, out, N_NODES);
}

// Round 9
// 446.828 us; speedup vs baseline: 5.1208x; 5.1208x over previous
//
#include <hip/hip_runtime.h>

#define N_NODES 100000
#define N_EDGES 3200000
#define IN_CH 128
#define HID_CH 64
#define OUT_CH 32

#define BSHIFT 7
#define BNODES 128                                   // nodes per bucket
#define NBUCK ((N_NODES + BNODES - 1) / BNODES)      // 782
#define PCHUNK 6144                                  // edges per partition WG
#define NPCHK ((N_EDGES + PCHUNK - 1) / PCHUNK)      // 521
#define BCAP 6144                                    // bucket capacity (mean 4092, sigma 64)

typedef unsigned long long ull;
typedef unsigned int u32;
typedef _Float16 h2v __attribute__((ext_vector_type(2)));   // half2

// ---------------- partition pass 1: global bucket counts ----------------
__global__ __launch_bounds__(256) void pcount_kernel(const int* __restrict__ dst,
                                                     u32* __restrict__ gcnt, int nE) {
    __shared__ u32 cntL[NBUCK];
    int tid = threadIdx.x;
    for (int i = tid; i < NBUCK; i += 256) cntL[i] = 0;
    __syncthreads();
    int e0 = blockIdx.x * PCHUNK;
    for (int i = tid; i < PCHUNK; i += 256) {
        int e = e0 + i;
        if (e < nE) atomicAdd(&cntL[dst[e] >> BSHIFT], 1u);
    }
    __syncthreads();
    for (int i = tid; i < NBUCK; i += 256)
        if (cntL[i]) atomicAdd(&gcnt[i], cntL[i]);
}

// ---------------- partition pass 2: scan bucket counts -> base, cursor ----------------
__global__ __launch_bounds__(256) void scanb_kernel(const u32* __restrict__ gcnt,
                                                    int* __restrict__ base,
                                                    int* __restrict__ gcur) {
    __shared__ int temp[256];
    int tid = threadIdx.x;
    int c[4]; int s = 0;
#pragma unroll
    for (int k = 0; k < 4; ++k) {
        int j = tid * 4 + k;
        c[k] = (j < NBUCK) ? (int)gcnt[j] : 0;
        s += c[k];
    }
    temp[tid] = s; __syncthreads();
    for (int d = 1; d < 256; d <<= 1) {
        int v = (tid >= d) ? temp[tid - d] : 0; __syncthreads();
        temp[tid] += v; __syncthreads();
    }
    int run = temp[tid] - s;   // exclusive
#pragma unroll
    for (int k = 0; k < 4; ++k) {
        int j = tid * 4 + k;
        if (j < NBUCK) { base[j] = run; gcur[j] = run; }
        run += c[k];
    }
    if (tid == 255) base[NBUCK] = run;   // == nE
}

// ---------------- partition pass 3: LDS-staged scatter into bucket-major COO ----------------
// ebuck record: .x = src(17b) | dstLocal(7b)<<17 ; .y = w (dequantized from 16-bit fixed)
__global__ __launch_bounds__(256) void pscatter_kernel(const int* __restrict__ src,
                                                       const int* __restrict__ dst,
                                                       const float* __restrict__ w,
                                                       int* __restrict__ gcur,
                                                       int2* __restrict__ ebuck, int nE) {
    __shared__ ull staging[PCHUNK];   // src17 | dst17<<17 | w16<<34
    __shared__ u32 cntL[NBUCK];       // counts, later per-chunk global segment base
    __shared__ u32 ofsL[NBUCK];
    __shared__ u32 curL[NBUCK];
    __shared__ int temp[256];
    int tid = threadIdx.x;
    int e0 = blockIdx.x * PCHUNK;
    int nb = nE - e0; if (nb > PCHUNK) nb = PCHUNK;

    for (int i = tid; i < NBUCK; i += 256) cntL[i] = 0;
    __syncthreads();
    // local histogram
    for (int i = tid; i < PCHUNK; i += 256) {
        int e = e0 + i;
        if (e < nE) atomicAdd(&cntL[dst[e] >> BSHIFT], 1u);
    }
    __syncthreads();
    // local exclusive scan -> ofsL (frozen) + curL (mutable)
    int c[4]; int s = 0;
#pragma unroll
    for (int k = 0; k < 4; ++k) {
        int j = tid * 4 + k;
        c[k] = (j < NBUCK) ? (int)cntL[j] : 0;
        s += c[k];
    }
    temp[tid] = s; __syncthreads();
    for (int d = 1; d < 256; d <<= 1) {
        int v = (tid >= d) ? temp[tid - d] : 0; __syncthreads();
        temp[tid] += v; __syncthreads();
    }
    int run = temp[tid] - s;
#pragma unroll
    for (int k = 0; k < 4; ++k) {
        int j = tid * 4 + k;
        if (j < NBUCK) { ofsL[j] = (u32)run; curL[j] = (u32)run; }
        run += c[k];
    }
    __syncthreads();
    // stage records grouped by bucket
    for (int i = tid; i < PCHUNK; i += 256) {
        int e = e0 + i;
        if (e < nE) {
            int d = dst[e];
            u32 w16 = (u32)(w[e] * 65535.f + 0.5f); if (w16 > 65535u) w16 = 65535u;
            u32 slot = atomicAdd(&curL[d >> BSHIFT], 1u);
            staging[slot] = (ull)(u32)src[e] | ((ull)(u32)d << 17) | ((ull)w16 << 34);
        }
    }
    __syncthreads();
    // reserve global ranges per bucket (cntL := this chunk's global segment base)
    for (int b = tid; b < NBUCK; b += 256) {
        u32 cc = curL[b] - ofsL[b];
        if (cc) cntL[b] = (u32)atomicAdd(&gcur[b], (int)cc);
    }
    __syncthreads();
    // coalesced-ish flush (bucket-grouped staging -> contiguous global segments)
    for (int sI = tid; sI < nb; sI += 256) {
        ull r = staging[sI];
        int srcn = (int)(r & 0x1FFFF);
        int d    = (int)((r >> 17) & 0x1FFFF);
        u32 w16  = (u32)((r >> 34) & 0xFFFF);
        int b = d >> BSHIFT;
        int dest = (int)cntL[b] + (sI - (int)ofsL[b]);
        float wf = (float)w16 * (1.f / 65535.f);
        ebuck[dest] = make_int2(srcn | ((d & (BNODES - 1)) << 17), __float_as_int(wf));
    }
}

// ---------------- in-bucket node sort (IN PLACE) + rowptr + dinv ----------------
// block b sorts segment [base[b], base[b+1]) by dstLocal via LDS staging; strips dl.
__global__ __launch_bounds__(256) void bsort_kernel(const int* __restrict__ base,
                                                    int2* __restrict__ ebuck,
                                                    int* __restrict__ rowptr,
                                                    float* __restrict__ dinv, int n) {
    __shared__ int2 staging[BCAP];      // 48KB
    __shared__ u32 cntL[BNODES];
    __shared__ u32 curL[BNODES];
    __shared__ float degL[BNODES];
    __shared__ int scn[BNODES];
    int tid = threadIdx.x, b = blockIdx.x;
    int beg = base[b], end = base[b + 1];
    int L = end - beg; if (L > BCAP) L = BCAP;   // impossible in practice; guards LDS

    if (tid < BNODES) { cntL[tid] = 0; degL[tid] = 0.f; }
    __syncthreads();
    // pass A: per-node counts + weighted degree
    for (int i = beg + tid; i < end; i += 256) {
        int2 r = ebuck[i];
        int dl = (r.x >> 17) & (BNODES - 1);
        atomicAdd(&cntL[dl], 1u);
        atomicAdd(&degL[dl], __int_as_float(r.y));
    }
    __syncthreads();
    // inclusive Hillis-Steele scan over 128 counts
    if (tid < BNODES) scn[tid] = (int)cntL[tid];
    __syncthreads();
    for (int d = 1; d < BNODES; d <<= 1) {
        int v = 0;
        if (tid < BNODES && tid >= d) v = scn[tid - d];
        __syncthreads();
        if (tid < BNODES) scn[tid] += v;
        __syncthreads();
    }
    if (tid < BNODES) {
        int excl = scn[tid] - (int)cntL[tid];
        curL[tid] = (u32)excl;
        int node = b * BNODES + tid;
        if (node < n) {
            rowptr[node] = beg + excl;
            dinv[node] = rsqrtf(degL[tid] + 1.f);
        }
    }
    if (b == 0 && tid == 0) rowptr[n] = N_EDGES;
    __syncthreads();
    // pass B: stage node-sorted, strip dl
    for (int i = beg + tid; i < end; i += 256) {
        int2 r = ebuck[i];
        int dl = (r.x >> 17) & (BNODES - 1);
        u32 slot = atomicAdd(&curL[dl], 1u);
        if (slot < (u32)BCAP) staging[slot] = make_int2(r.x & 0x1FFFF, r.y);
    }
    __syncthreads();
    // coalesced in-place flush
    for (int i = tid; i < L; i += 256) ebuck[beg + i] = staging[i];
}

// ---------------- gemm1: g1[n] = dinv[n] * (x[n] @ W1), fp16 ----------------
__global__ __launch_bounds__(256) void gemm1_kernel(const float* __restrict__ X,
                                                    const float* __restrict__ Wm,
                                                    const float* __restrict__ dinv,
                                                    _Float16* __restrict__ G, int n) {
    constexpr int INC = IN_CH, OUTC = HID_CH, TN = OUTC / 16;
    __shared__ float Ws[INC][OUTC];
    __shared__ float Xs[64][INC + 4];

    const int tid = threadIdx.x;
    const int row0 = blockIdx.x * 64;

    for (int i = tid; i < INC * OUTC / 4; i += 256)
        reinterpret_cast<float4*>(&Ws[0][0])[i] = reinterpret_cast<const float4*>(Wm)[i];
    for (int i = tid; i < 64 * INC / 4; i += 256) {
        int r = i / (INC / 4);
        int c = (i % (INC / 4)) * 4;
        float4 v = make_float4(0.f, 0.f, 0.f, 0.f);
        if (row0 + r < n)
            v = *reinterpret_cast<const float4*>(X + (size_t)(row0 + r) * INC + c);
        *reinterpret_cast<float4*>(&Xs[r][c]) = v;
    }
    __syncthreads();

    const int cg = tid & 15;
    const int rg = tid >> 4;

    float acc[4][TN];
#pragma unroll
    for (int i = 0; i < 4; ++i)
#pragma unroll
        for (int j = 0; j < TN; ++j) acc[i][j] = 0.f;

    for (int k = 0; k < INC; ++k) {
        float wv[TN];
#pragma unroll
        for (int j = 0; j < TN; ++j) wv[j] = Ws[k][cg * TN + j];
#pragma unroll
        for (int i = 0; i < 4; ++i) {
            float xv = Xs[rg * 4 + i][k];
#pragma unroll
            for (int j = 0; j < TN; ++j) acc[i][j] = fmaf(xv, wv[j], acc[i][j]);
        }
    }

#pragma unroll
    for (int i = 0; i < 4; ++i) {
        int row = row0 + rg * 4 + i;
        if (row < n) {
            float di = dinv[row];
#pragma unroll
            for (int j = 0; j < TN; ++j)
                G[(size_t)row * OUTC + cg * TN + j] = (_Float16)(di * acc[i][j]);
        }
    }
}

// ---------------- layer1 aggregate (gather, fp16, 2 edges in flight)
//  hidden = relu(di*(sum w*g1[src] + g1[node]) + b1); g2h = di*(hidden @ W2) fp16 ----------------
__global__ __launch_bounds__(256) void agg1_kernel(
    const int* __restrict__ rowptr, const int2* __restrict__ epack,
    const h2v* __restrict__ g1, const float* __restrict__ dinv,
    const float* __restrict__ b1, const float* __restrict__ W2,
    _Float16* __restrict__ g2h, int n)
{
    __shared__ float W2s[HID_CH * OUT_CH];
    for (int i = threadIdx.x; i < HID_CH * OUT_CH / 4; i += 256)
        reinterpret_cast<float4*>(W2s)[i] = reinterpret_cast<const float4*>(W2)[i];
    __syncthreads();

    const int wid = threadIdx.x >> 6;
    const int lane = threadIdx.x & 63;
    const int p = lane & 31;      // channel-pair index (channels 2p, 2p+1)
    const int sub = lane >> 5;    // which edge of the in-flight pair
    const int node = blockIdx.x * 4 + wid;
    if (node >= n) return;

    const int beg = rowptr[node], end = rowptr[node + 1];

    float ax = 0.f, ay = 0.f;
    for (int i = beg; i < end; i += 64) {
        int nb = end - i; if (nb > 64) nb = 64;
        int2 ep = (i + lane < end) ? epack[i + lane] : make_int2(0, 0);
        for (int j = 0; j < nb; j += 2) {
            int eidx = j + sub;                        // OOR lanes carry (0,0) -> w=0
            int s = __shfl(ep.x, eidx);
            float wv = __int_as_float(__shfl(ep.y, eidx));
            h2v hv = g1[(size_t)s * 32 + p];
            ax = fmaf(wv, (float)hv.x, ax);
            ay = fmaf(wv, (float)hv.y, ay);
        }
    }
    ax += __shfl_xor(ax, 32);
    ay += __shfl_xor(ay, 32);

    const float di = dinv[node];
    h2v selfv = g1[(size_t)node * 32 + p];
    float2 bp = reinterpret_cast<const float2*>(b1)[p];
    float hx = fmaxf(di * (ax + (float)selfv.x) + bp.x, 0.f);
    float hy = fmaxf(di * (ay + (float)selfv.y) + bp.y, 0.f);

    // fused GEMM2: acc2[o] = sum_{c} hidden[c] * W2[c][o]; sub splits c-range
    const int o = lane & 31;
    float acc2 = 0.f;
#pragma unroll
    for (int cp = 0; cp < 16; ++cp) {
        int q = sub * 16 + cp;
        float hcx = __shfl(hx, q);
        float hcy = __shfl(hy, q);
        acc2 = fmaf(hcx, W2s[(2 * q + 0) * OUT_CH + o], acc2);
        acc2 = fmaf(hcy, W2s[(2 * q + 1) * OUT_CH + o], acc2);
    }
    acc2 += __shfl_xor(acc2, 32);
    if (sub == 0) g2h[(size_t)node * OUT_CH + o] = (_Float16)(di * acc2);
}

// ---------------- layer2 aggregate (gather, fp16, 2 edges in flight) ----------------
// out = di*(sum w*g2h[src] + g2h[node]) + b2
__global__ __launch_bounds__(256) void agg2_kernel(
    const int* __restrict__ rowptr, const int2* __restrict__ epack,
    const h2v* __restrict__ g2, const float* __restrict__ dinv,
    const float* __restrict__ b2, float* __restrict__ out, int n)
{
    const int grp = threadIdx.x >> 5;      // 8 groups per block
    const int g = threadIdx.x & 31;
    const int p = g & 15;
    const int sub = g >> 4;
    const int node = blockIdx.x * 8 + grp;
    if (node >= n) return;

    const int beg = rowptr[node], end = rowptr[node + 1];

    float ax = 0.f, ay = 0.f;
    for (int i = beg; i < end; i += 32) {
        int nb = end - i; if (nb > 32) nb = 32;
        int2 ep = (i + g < end) ? epack[i + g] : make_int2(0, 0);
        for (int j = 0; j < nb; j += 2) {
            int eidx = j + sub;
            int s = __shfl(ep.x, eidx, 32);
            float wv = __int_as_float(__shfl(ep.y, eidx, 32));
            h2v hv = g2[(size_t)s * 16 + p];
            ax = fmaf(wv, (float)hv.x, ax);
            ay = fmaf(wv, (float)hv.y, ay);
        }
    }
    ax += __shfl_xor(ax, 16, 32);
    ay += __shfl_xor(ay, 16, 32);

    if (sub == 0) {
        const float di = dinv[node];
        h2v selfv = g2[(size_t)node * 16 + p];
        float2 bp = reinterpret_cast<const float2*>(b2)[p];
        float2 r;
        r.x = di * (ax + (float)selfv.x) + bp.x;
        r.y = di * (ay + (float)selfv.y) + bp.y;
        reinterpret_cast<float2*>(out)[(size_t)node * 16 + p] = r;
    }
}

extern "C" void kernel_launch(void* const* d_in, const int* in_sizes, int n_in,
                              void* d_out, int out_size, void* d_ws, size_t ws_size,
                              hipStream_t stream) {
    const float* x   = (const float*)d_in[0];
    const int*   ei  = (const int*)d_in[1];
    const float* w   = (const float*)d_in[2];
    const float* W1  = (const float*)d_in[3];
    const float* b1  = (const float*)d_in[4];
    const float* W2  = (const float*)d_in[5];
    const float* b2  = (const float*)d_in[6];
    float* out = (float*)d_out;

    const int* src = ei;
    const int* dst = ei + N_EDGES;

    // workspace ~45.7MB (well under the >=64.5MB proven in round 2)
    char* ws = (char*)d_ws;
    size_t off = 0;
    auto alloc = [&](size_t b) { size_t p = off; off += (b + 255) & ~(size_t)255; return p; };
    u32*      gcnt   = (u32*)(ws + alloc((size_t)NBUCK * 4));
    int*      base   = (int*)(ws + alloc((size_t)(NBUCK + 1) * 4));
    int*      gcur   = (int*)(ws + alloc((size_t)NBUCK * 4));
    int*      rowptr = (int*)(ws + alloc((size_t)(N_NODES + 1) * 4));
    float*    dinv   = (float*)(ws + alloc((size_t)N_NODES * 4));
    int2*     ebuck  = (int2*)(ws + alloc((size_t)N_EDGES * 8));   // -> sorted in place
    _Float16* g1     = (_Float16*)(ws + alloc((size_t)N_NODES * HID_CH * 2));
    _Float16* g2h    = (_Float16*)(ws + alloc((size_t)N_NODES * OUT_CH * 2));

    hipMemsetAsync(gcnt, 0, (size_t)NBUCK * 4, stream);

    // bucket partition (coalesced) -> in-bucket sort -> CSR + dinv
    pcount_kernel<<<NPCHK, 256, 0, stream>>>(dst, gcnt, N_EDGES);
    scanb_kernel<<<1, 256, 0, stream>>>(gcnt, base, gcur);
    pscatter_kernel<<<NPCHK, 256, 0, stream>>>(src, dst, w, gcur, ebuck, N_EDGES);
    bsort_kernel<<<NBUCK, 256, 0, stream>>>(base, ebuck, rowptr, dinv, N_NODES);

    // g1 = dinv * (x @ W1)
    gemm1_kernel<<<(N_NODES + 63) / 64, 256, 0, stream>>>(x, W1, dinv, g1, N_NODES);

    // layer1 aggregate + ReLU + fused GEMM2 -> g2h = dinv * h2
    agg1_kernel<<<(N_NODES + 3) / 4, 256, 0, stream>>>(rowptr, ebuck, (const h2v*)g1, dinv, b1, W2, g2h, N_NODES);

    // layer2 aggregate -> out
    agg2_kernel<<<(N_NODES + 7) / 8, 256, 0, stream>>>(rowptr, ebuck, (const h2v*)g2h, dinv, b2, out, N_NODES);
}

// Round 12
// 400.005 us; speedup vs baseline: 5.7202x; 1.1171x over previous
//
#include <hip/hip_runtime.h>

#define N_NODES 100000
#define N_EDGES 3200000
#define IN_CH 128
#define HID_CH 64
#define OUT_CH 32

#define BSHIFT 7
#define BNODES 128                                   // nodes per bucket
#define NBUCK ((N_NODES + BNODES - 1) / BNODES)      // 782
#define PCHUNK 6144                                  // edges per partition WG
#define NPCHK ((N_EDGES + PCHUNK - 1) / PCHUNK)      // 521
#define BCAP 6144                                    // bucket capacity (mean 4092, sigma 64)

typedef unsigned long long ull;
typedef unsigned int u32;
typedef _Float16 h4v __attribute__((ext_vector_type(4)));   // half4 (8B)

// ---------------- partition pass 1: global bucket counts ----------------
__global__ __launch_bounds__(256) void pcount_kernel(const int* __restrict__ dst,
                                                     u32* __restrict__ gcnt, int nE) {
    __shared__ u32 cntL[NBUCK];
    int tid = threadIdx.x;
    for (int i = tid; i < NBUCK; i += 256) cntL[i] = 0;
    __syncthreads();
    int e0 = blockIdx.x * PCHUNK;
    for (int i = tid; i < PCHUNK; i += 256) {
        int e = e0 + i;
        if (e < nE) atomicAdd(&cntL[dst[e] >> BSHIFT], 1u);
    }
    __syncthreads();
    for (int i = tid; i < NBUCK; i += 256)
        if (cntL[i]) atomicAdd(&gcnt[i], cntL[i]);
}

// ---------------- partition pass 2: scan bucket counts -> base, cursor ----------------
__global__ __launch_bounds__(256) void scanb_kernel(const u32* __restrict__ gcnt,
                                                    int* __restrict__ base,
                                                    int* __restrict__ gcur) {
    __shared__ int temp[256];
    int tid = threadIdx.x;
    int c[4]; int s = 0;
#pragma unroll
    for (int k = 0; k < 4; ++k) {
        int j = tid * 4 + k;
        c[k] = (j < NBUCK) ? (int)gcnt[j] : 0;
        s += c[k];
    }
    temp[tid] = s; __syncthreads();
    for (int d = 1; d < 256; d <<= 1) {
        int v = (tid >= d) ? temp[tid - d] : 0; __syncthreads();
        temp[tid] += v; __syncthreads();
    }
    int run = temp[tid] - s;   // exclusive
#pragma unroll
    for (int k = 0; k < 4; ++k) {
        int j = tid * 4 + k;
        if (j < NBUCK) { base[j] = run; gcur[j] = run; }
        run += c[k];
    }
    if (tid == 255) base[NBUCK] = run;   // == nE
}

// ---------------- partition pass 3: LDS-staged scatter into bucket-major COO ----------------
// ebuck record: .x = src(17b) | dstLocal(7b)<<17 ; .y = w (dequantized from 16-bit fixed)
__global__ __launch_bounds__(256) void pscatter_kernel(const int* __restrict__ src,
                                                       const int* __restrict__ dst,
                                                       const float* __restrict__ w,
                                                       int* __restrict__ gcur,
                                                       int2* __restrict__ ebuck, int nE) {
    __shared__ ull staging[PCHUNK];   // src17 | dst17<<17 | w16<<34
    __shared__ u32 cntL[NBUCK];       // counts, later per-chunk global segment base
    __shared__ u32 ofsL[NBUCK];
    __shared__ u32 curL[NBUCK];
    __shared__ int temp[256];
    int tid = threadIdx.x;
    int e0 = blockIdx.x * PCHUNK;
    int nb = nE - e0; if (nb > PCHUNK) nb = PCHUNK;

    for (int i = tid; i < NBUCK; i += 256) cntL[i] = 0;
    __syncthreads();
    // local histogram
    for (int i = tid; i < PCHUNK; i += 256) {
        int e = e0 + i;
        if (e < nE) atomicAdd(&cntL[dst[e] >> BSHIFT], 1u);
    }
    __syncthreads();
    // local exclusive scan -> ofsL (frozen) + curL (mutable)
    int c[4]; int s = 0;
#pragma unroll
    for (int k = 0; k < 4; ++k) {
        int j = tid * 4 + k;
        c[k] = (j < NBUCK) ? (int)cntL[j] : 0;
        s += c[k];
    }
    temp[tid] = s; __syncthreads();
    for (int d = 1; d < 256; d <<= 1) {
        int v = (tid >= d) ? temp[tid - d] : 0; __syncthreads();
        temp[tid] += v; __syncthreads();
    }
    int run = temp[tid] - s;
#pragma unroll
    for (int k = 0; k < 4; ++k) {
        int j = tid * 4 + k;
        if (j < NBUCK) { ofsL[j] = (u32)run; curL[j] = (u32)run; }
        run += c[k];
    }
    __syncthreads();
    // stage records grouped by bucket
    for (int i = tid; i < PCHUNK; i += 256) {
        int e = e0 + i;
        if (e < nE) {
            int d = dst[e];
            u32 w16 = (u32)(w[e] * 65535.f + 0.5f); if (w16 > 65535u) w16 = 65535u;
            u32 slot = atomicAdd(&curL[d >> BSHIFT], 1u);
            staging[slot] = (ull)(u32)src[e] | ((ull)(u32)d << 17) | ((ull)w16 << 34);
        }
    }
    __syncthreads();
    // reserve global ranges per bucket (cntL := this chunk's global segment base)
    for (int b = tid; b < NBUCK; b += 256) {
        u32 cc = curL[b] - ofsL[b];
        if (cc) cntL[b] = (u32)atomicAdd(&gcur[b], (int)cc);
    }
    __syncthreads();
    // coalesced-ish flush (bucket-grouped staging -> contiguous global segments)
    for (int sI = tid; sI < nb; sI += 256) {
        ull r = staging[sI];
        int srcn = (int)(r & 0x1FFFF);
        int d    = (int)((r >> 17) & 0x1FFFF);
        u32 w16  = (u32)((r >> 34) & 0xFFFF);
        int b = d >> BSHIFT;
        int dest = (int)cntL[b] + (sI - (int)ofsL[b]);
        float wf = (float)w16 * (1.f / 65535.f);
        ebuck[dest] = make_int2(srcn | ((d & (BNODES - 1)) << 17), __float_as_int(wf));
    }
}

// ---------------- in-bucket node sort (IN PLACE) + rowptr + dinv ----------------
__global__ __launch_bounds__(256) void bsort_kernel(const int* __restrict__ base,
                                                    int2* __restrict__ ebuck,
                                                    int* __restrict__ rowptr,
                                                    float* __restrict__ dinv, int n) {
    __shared__ int2 staging[BCAP];      // 48KB
    __shared__ u32 cntL[BNODES];
    __shared__ u32 curL[BNODES];
    __shared__ float degL[BNODES];
    __shared__ int scn[BNODES];
    int tid = threadIdx.x, b = blockIdx.x;
    int beg = base[b], end = base[b + 1];
    int L = end - beg; if (L > BCAP) L = BCAP;   // impossible in practice; guards LDS

    if (tid < BNODES) { cntL[tid] = 0; degL[tid] = 0.f; }
    __syncthreads();
    // pass A: per-node counts + weighted degree
    for (int i = beg + tid; i < end; i += 256) {
        int2 r = ebuck[i];
        int dl = (r.x >> 17) & (BNODES - 1);
        atomicAdd(&cntL[dl], 1u);
        atomicAdd(&degL[dl], __int_as_float(r.y));
    }
    __syncthreads();
    if (tid < BNODES) scn[tid] = (int)cntL[tid];
    __syncthreads();
    for (int d = 1; d < BNODES; d <<= 1) {
        int v = 0;
        if (tid < BNODES && tid >= d) v = scn[tid - d];
        __syncthreads();
        if (tid < BNODES) scn[tid] += v;
        __syncthreads();
    }
    if (tid < BNODES) {
        int excl = scn[tid] - (int)cntL[tid];
        curL[tid] = (u32)excl;
        int node = b * BNODES + tid;
        if (node < n) {
            rowptr[node] = beg + excl;
            dinv[node] = rsqrtf(degL[tid] + 1.f);
        }
    }
    if (b == 0 && tid == 0) rowptr[n] = N_EDGES;
    __syncthreads();
    // pass B: stage node-sorted, strip dl
    for (int i = beg + tid; i < end; i += 256) {
        int2 r = ebuck[i];
        int dl = (r.x >> 17) & (BNODES - 1);
        u32 slot = atomicAdd(&curL[dl], 1u);
        if (slot < (u32)BCAP) staging[slot] = make_int2(r.x & 0x1FFFF, r.y);
    }
    __syncthreads();
    for (int i = tid; i < L; i += 256) ebuck[beg + i] = staging[i];
}

// ---------------- gemm1: g1[n] = dinv[n] * (x[n] @ W1), fp16 ----------------
__global__ __launch_bounds__(256) void gemm1_kernel(const float* __restrict__ X,
                                                    const float* __restrict__ Wm,
                                                    const float* __restrict__ dinv,
                                                    _Float16* __restrict__ G, int n) {
    constexpr int INC = IN_CH, OUTC = HID_CH, TN = OUTC / 16;
    __shared__ float Ws[INC][OUTC];
    __shared__ float Xs[64][INC + 4];

    const int tid = threadIdx.x;
    const int row0 = blockIdx.x * 64;

    for (int i = tid; i < INC * OUTC / 4; i += 256)
        reinterpret_cast<float4*>(&Ws[0][0])[i] = reinterpret_cast<const float4*>(Wm)[i];
    for (int i = tid; i < 64 * INC / 4; i += 256) {
        int r = i / (INC / 4);
        int c = (i % (INC / 4)) * 4;
        float4 v = make_float4(0.f, 0.f, 0.f, 0.f);
        if (row0 + r < n)
            v = *reinterpret_cast<const float4*>(X + (size_t)(row0 + r) * INC + c);
        *reinterpret_cast<float4*>(&Xs[r][c]) = v;
    }
    __syncthreads();

    const int cg = tid & 15;
    const int rg = tid >> 4;

    float acc[4][TN];
#pragma unroll
    for (int i = 0; i < 4; ++i)
#pragma unroll
        for (int j = 0; j < TN; ++j) acc[i][j] = 0.f;

    for (int k = 0; k < INC; ++k) {
        float wv[TN];
#pragma unroll
        for (int j = 0; j < TN; ++j) wv[j] = Ws[k][cg * TN + j];
#pragma unroll
        for (int i = 0; i < 4; ++i) {
            float xv = Xs[rg * 4 + i][k];
#pragma unroll
            for (int j = 0; j < TN; ++j) acc[i][j] = fmaf(xv, wv[j], acc[i][j]);
        }
    }

#pragma unroll
    for (int i = 0; i < 4; ++i) {
        int row = row0 + rg * 4 + i;
        if (row < n) {
            float di = dinv[row];
#pragma unroll
            for (int j = 0; j < TN; ++j)
                G[(size_t)row * OUTC + cg * TN + j] = (_Float16)(di * acc[i][j]);
        }
    }
}

// ---------------- layer1 aggregate: 4 edges in flight, 8B gathers ----------------
// wave per node. lane = {q = lane&15 (channel quad: ch 4q..4q+3), sub = lane>>4 (edge slot)}
// hidden = relu(di*(sum w*g1[src] + g1[node]) + b1); g2h = di*(hidden @ W2) fp16
__global__ __launch_bounds__(256) void agg1_kernel(
    const int* __restrict__ rowptr, const int2* __restrict__ epack,
    const h4v* __restrict__ g1q, const float* __restrict__ dinv,
    const float* __restrict__ b1, const float* __restrict__ W2,
    _Float16* __restrict__ g2h, int n)
{
    __shared__ float W2s[HID_CH * OUT_CH];
    for (int i = threadIdx.x; i < HID_CH * OUT_CH / 4; i += 256)
        reinterpret_cast<float4*>(W2s)[i] = reinterpret_cast<const float4*>(W2)[i];
    __syncthreads();

    const int wid = threadIdx.x >> 6;
    const int lane = threadIdx.x & 63;
    const int q = lane & 15;       // channel quad (4 channels: 4q..4q+3)
    const int sub = lane >> 4;     // 4 edges in flight
    const int node = blockIdx.x * 4 + wid;
    if (node >= n) return;

    const int beg = rowptr[node], end = rowptr[node + 1];

    float a0 = 0.f, a1 = 0.f, a2 = 0.f, a3 = 0.f;
    for (int i = beg; i < end; i += 64) {
        int nb = end - i; if (nb > 64) nb = 64;
        int2 ep = (i + lane < end) ? epack[i + lane] : make_int2(0, 0);
        for (int j = 0; j < nb; j += 4) {
            int eidx = j + sub;                   // <=63; OOR slots carry (0,0) -> w=0
            int s = __shfl(ep.x, eidx);
            float wv = __int_as_float(__shfl(ep.y, eidx));
            h4v hv = g1q[(size_t)s * 16 + q];
            a0 = fmaf(wv, (float)hv.x, a0);
            a1 = fmaf(wv, (float)hv.y, a1);
            a2 = fmaf(wv, (float)hv.z, a2);
            a3 = fmaf(wv, (float)hv.w, a3);
        }
    }
    // combine 4 edge slots (lanes q, q+16, q+32, q+48 — q invariant under ^16/^32)
    a0 += __shfl_xor(a0, 16); a0 += __shfl_xor(a0, 32);
    a1 += __shfl_xor(a1, 16); a1 += __shfl_xor(a1, 32);
    a2 += __shfl_xor(a2, 16); a2 += __shfl_xor(a2, 32);
    a3 += __shfl_xor(a3, 16); a3 += __shfl_xor(a3, 32);

    const float di = dinv[node];
    h4v sv = g1q[(size_t)node * 16 + q];
    float4 bp = reinterpret_cast<const float4*>(b1)[q];
    float h0 = fmaxf(di * (a0 + (float)sv.x) + bp.x, 0.f);
    float h1 = fmaxf(di * (a1 + (float)sv.y) + bp.y, 0.f);
    float h2 = fmaxf(di * (a2 + (float)sv.z) + bp.z, 0.f);
    float h3 = fmaxf(di * (a3 + (float)sv.w) + bp.w, 0.f);

    // fused GEMM2. Each lane owns outputs {oa, oa+16}, oa = lane&15 (invariant under
    // the ^16/^32 reduction — round-10 bug was o=lane&31, NOT invariant under ^16).
    // sub s accumulates the 16-channel slice cq = 4s..4s+3; xor-combine over subs.
    const int oa = lane & 15;
    float accA = 0.f, accB = 0.f;
#pragma unroll
    for (int t = 0; t < 4; ++t) {
        int cq = sub * 4 + t;                 // source lane holding channels 4cq..4cq+3
        float c0 = __shfl(h0, cq);
        float c1 = __shfl(h1, cq);
        float c2 = __shfl(h2, cq);
        float c3 = __shfl(h3, cq);
        accA = fmaf(c0, W2s[(4 * cq + 0) * OUT_CH + oa], accA);
        accA = fmaf(c1, W2s[(4 * cq + 1) * OUT_CH + oa], accA);
        accA = fmaf(c2, W2s[(4 * cq + 2) * OUT_CH + oa], accA);
        accA = fmaf(c3, W2s[(4 * cq + 3) * OUT_CH + oa], accA);
        accB = fmaf(c0, W2s[(4 * cq + 0) * OUT_CH + oa + 16], accB);
        accB = fmaf(c1, W2s[(4 * cq + 1) * OUT_CH + oa + 16], accB);
        accB = fmaf(c2, W2s[(4 * cq + 2) * OUT_CH + oa + 16], accB);
        accB = fmaf(c3, W2s[(4 * cq + 3) * OUT_CH + oa + 16], accB);
    }
    accA += __shfl_xor(accA, 16); accA += __shfl_xor(accA, 32);
    accB += __shfl_xor(accB, 16); accB += __shfl_xor(accB, 32);
    if (lane < 16) {
        g2h[(size_t)node * OUT_CH + oa]      = (_Float16)(di * accA);
        g2h[(size_t)node * OUT_CH + oa + 16] = (_Float16)(di * accB);
    }
}

// ---------------- layer2 aggregate: 4 edges in flight, 8B gathers ----------------
// 32-lane group per node. lane-in-group g = {q = g&7 (ch 4q..4q+3), sub = g>>3}
// out = di*(sum w*g2[src] + g2[node]) + b2
__global__ __launch_bounds__(256) void agg2_kernel(
    const int* __restrict__ rowptr, const int2* __restrict__ epack,
    const h4v* __restrict__ g2q, const float* __restrict__ dinv,
    const float* __restrict__ b2, float* __restrict__ out, int n)
{
    const int grp = threadIdx.x >> 5;      // 8 groups per block
    const int g = threadIdx.x & 31;
    const int q = g & 7;
    const int sub = g >> 3;
    const int node = blockIdx.x * 8 + grp;
    if (node >= n) return;

    const int beg = rowptr[node], end = rowptr[node + 1];

    float a0 = 0.f, a1 = 0.f, a2 = 0.f, a3 = 0.f;
    for (int i = beg; i < end; i += 32) {
        int nb = end - i; if (nb > 32) nb = 32;
        int2 ep = (i + g < end) ? epack[i + g] : make_int2(0, 0);
        for (int j = 0; j < nb; j += 4) {
            int eidx = j + sub;
            int s = __shfl(ep.x, eidx, 32);
            float wv = __int_as_float(__shfl(ep.y, eidx, 32));
            h4v hv = g2q[(size_t)s * 8 + q];
            a0 = fmaf(wv, (float)hv.x, a0);
            a1 = fmaf(wv, (float)hv.y, a1);
            a2 = fmaf(wv, (float)hv.z, a2);
            a3 = fmaf(wv, (float)hv.w, a3);
        }
    }
    // q = g&7 invariant under ^8 and ^16 within the 32-lane group
    a0 += __shfl_xor(a0, 8, 32); a0 += __shfl_xor(a0, 16, 32);
    a1 += __shfl_xor(a1, 8, 32); a1 += __shfl_xor(a1, 16, 32);
    a2 += __shfl_xor(a2, 8, 32); a2 += __shfl_xor(a2, 16, 32);
    a3 += __shfl_xor(a3, 8, 32); a3 += __shfl_xor(a3, 16, 32);

    if (sub == 0) {
        const float di = dinv[node];
        h4v sv = g2q[(size_t)node * 8 + q];
        float4 bp = reinterpret_cast<const float4*>(b2)[q];
        float4 r;
        r.x = di * (a0 + (float)sv.x) + bp.x;
        r.y = di * (a1 + (float)sv.y) + bp.y;
        r.z = di * (a2 + (float)sv.z) + bp.z;
        r.w = di * (a3 + (float)sv.w) + bp.w;
        reinterpret_cast<float4*>(out)[(size_t)node * 8 + q] = r;
    }
}

extern "C" void kernel_launch(void* const* d_in, const int* in_sizes, int n_in,
                              void* d_out, int out_size, void* d_ws, size_t ws_size,
                              hipStream_t stream) {
    const float* x   = (const float*)d_in[0];
    const int*   ei  = (const int*)d_in[1];
    const float* w   = (const float*)d_in[2];
    const float* W1  = (const float*)d_in[3];
    const float* b1  = (const float*)d_in[4];
    const float* W2  = (const float*)d_in[5];
    const float* b2  = (const float*)d_in[6];
    float* out = (float*)d_out;

    const int* src = ei;
    const int* dst = ei + N_EDGES;

    // workspace ~45.7MB
    char* ws = (char*)d_ws;
    size_t off = 0;
    auto alloc = [&](size_t b) { size_t p = off; off += (b + 255) & ~(size_t)255; return p; };
    u32*      gcnt   = (u32*)(ws + alloc((size_t)NBUCK * 4));
    int*      base   = (int*)(ws + alloc((size_t)(NBUCK + 1) * 4));
    int*      gcur   = (int*)(ws + alloc((size_t)NBUCK * 4));
    int*      rowptr = (int*)(ws + alloc((size_t)(N_NODES + 1) * 4));
    float*    dinv   = (float*)(ws + alloc((size_t)N_NODES * 4));
    int2*     ebuck  = (int2*)(ws + alloc((size_t)N_EDGES * 8));   // -> sorted in place
    _Float16* g1     = (_Float16*)(ws + alloc((size_t)N_NODES * HID_CH * 2));
    _Float16* g2h    = (_Float16*)(ws + alloc((size_t)N_NODES * OUT_CH * 2));

    hipMemsetAsync(gcnt, 0, (size_t)NBUCK * 4, stream);

    // bucket partition (coalesced) -> in-bucket sort -> CSR + dinv
    pcount_kernel<<<NPCHK, 256, 0, stream>>>(dst, gcnt, N_EDGES);
    scanb_kernel<<<1, 256, 0, stream>>>(gcnt, base, gcur);
    pscatter_kernel<<<NPCHK, 256, 0, stream>>>(src, dst, w, gcur, ebuck, N_EDGES);
    bsort_kernel<<<NBUCK, 256, 0, stream>>>(base, ebuck, rowptr, dinv, N_NODES);

    // g1 = dinv * (x @ W1)
    gemm1_kernel<<<(N_NODES + 63) / 64, 256, 0, stream>>>(x, W1, dinv, g1, N_NODES);

    // layer1 aggregate + ReLU + fused GEMM2 -> g2h = dinv * h2
    agg1_kernel<<<(N_NODES + 3) / 4, 256, 0, stream>>>(rowptr, ebuck, (const h4v*)g1, dinv, b1, W2, g2h, N_NODES);

    // layer2 aggregate -> out
    agg2_kernel<<<(N_NODES + 7) / 8, 256, 0, stream>>>(rowptr, ebuck, (const h4v*)g2h, dinv, b2, out, N_NODES);
}